// Round 1
// baseline (207.645 us; speedup 1.0000x reference)
//
#include <hip/hip_runtime.h>
#include <cstdint>

#define Bq 16
#define Nq 512
#define Dq 12
#define HID 32
#define HEADS 4
#define Cq 8
#define NR 36   // 4 lsum rows + 32 acc rows

// ws layout (float offsets)
#define OFF_G     0u         // [b][n][32]       262144
#define OFF_AS    262144u    // [b][n][4]         32768
#define OFF_AD    294912u    // [b][n][4]         32768
#define OFF_TIT   327680u    // [b][h][n]        262144  (ti TRANSPOSED)
#define OFF_TJB   589824u    // [b][h][n]        262144
#define OFF_PACK  851968u    // u64 [b][i][8]    131072 floats (byte off %8==0)
#define OFF_PART  983040u    // [p][b][r=36][n]  P*294912

// ---- k0: per-node h, g, a_s, a_d. 8 nodes/block. ----
__global__ __launch_bounds__(256) void k0_node(
    const float* __restrict__ x, const float* __restrict__ Wp, const float* __restrict__ bp,
    const float* __restrict__ Wg, const float* __restrict__ att_src,
    const float* __restrict__ att_dst, float* __restrict__ ws) {
    __shared__ float xs[8 * Dq];
    __shared__ float hs[8][HID];
    int n_sub = threadIdx.x >> 5;
    int k = threadIdx.x & 31;
    int node0 = blockIdx.x * 8;
    if (threadIdx.x < 8 * Dq) xs[threadIdx.x] = x[(size_t)node0 * Dq + threadIdx.x];
    __syncthreads();
    float s = bp[k];
#pragma unroll
    for (int d = 0; d < Dq; d++) s = fmaf(Wp[k * Dq + d], xs[n_sub * Dq + d], s);
    hs[n_sub][k] = s > 0.f ? s : 0.f;
    __syncthreads();
    float g = 0.f;
#pragma unroll
    for (int d = 0; d < HID; d++) g = fmaf(Wg[k * HID + d], hs[n_sub][d], g);
    int nid = node0 + n_sub;
    ws[OFF_G + (size_t)nid * HID + k] = g;
    float ss = g * att_src[k];   // k = h*8+c
    float sd = g * att_dst[k];
#pragma unroll
    for (int off = 1; off < 8; off <<= 1) {
        ss += __shfl_xor(ss, off);
        sd += __shfl_xor(sd, off);
    }
    if ((k & 7) == 0) {
        int h = k >> 3;
        ws[OFF_AS + (size_t)nid * HEADS + h] = ss;
        ws[OFF_AD + (size_t)nid * HEADS + h] = sd;
    }
}

// ---- k1: aggregation partials, NO atomics. ----
// grid (P, 2, Bq), block 256. Thread owns j, loops ICH i's.
template <int ICH>
__global__ __launch_bounds__(256) void k1_aggregate(const int* __restrict__ adj,
                                                    float* __restrict__ ws) {
    constexpr int NCH = ICH / 8;
    int b = blockIdx.z;
    int p = blockIdx.x;
    int j = blockIdx.y * 256 + threadIdx.x;
    int i0 = p * ICH;
    __shared__ float gs[ICH * HID];
    __shared__ float ass[ICH * HEADS];
    {
        const float* gsrc = ws + OFF_G + ((size_t)b * Nq + i0) * HID;
        for (int t = threadIdx.x; t < ICH * HID; t += 256) gs[t] = gsrc[t];
        const float* asrc = ws + OFF_AS + ((size_t)b * Nq + i0) * HEADS;
        for (int t = threadIdx.x; t < ICH * HEADS; t += 256) ass[t] = asrc[t];
    }
    float adv[HEADS];
#pragma unroll
    for (int h = 0; h < HEADS; h++) adv[h] = ws[OFF_AD + ((size_t)b * Nq + j) * HEADS + h];
    __syncthreads();

    uint64_t* packed = (uint64_t*)(ws + OFF_PACK);
    const int* arow = adj + ((size_t)b * Nq + i0) * Nq + j;
    float lsum[HEADS] = {};
    float acc[HEADS][Cq] = {};
    int cur[8], nxt[8];
#pragma unroll
    for (int k = 0; k < 8; k++) cur[k] = arow[(size_t)k * Nq];
    for (int c = 0; c < NCH; c++) {
        if (c + 1 < NCH) {
#pragma unroll
            for (int k = 0; k < 8; k++) nxt[k] = arow[(size_t)((c + 1) * 8 + k) * Nq];
        }
#pragma unroll
        for (int k = 0; k < 8; k++) {
            int ii = c * 8 + k;
            int i = i0 + ii;
            unsigned long long m = __ballot(cur[k] != 0);
            if ((threadIdx.x & 63) == 0)
                packed[((size_t)b * Nq + i) * (Nq / 64) + (j >> 6)] = m;
            bool msk = (cur[k] != 0) || (i == j);
#pragma unroll
            for (int h = 0; h < HEADS; h++) {
                float z = ass[ii * HEADS + h] + adv[h];
                float lk = z > 0.f ? z : 0.2f * z;
                float e = msk ? __expf(lk) : 0.f;  // no max-shift: |z| small
                lsum[h] += e;
#pragma unroll
                for (int cc = 0; cc < Cq; cc++)
                    acc[h][cc] = fmaf(e, gs[ii * HID + h * Cq + cc], acc[h][cc]);
            }
        }
#pragma unroll
        for (int k = 0; k < 8; k++) cur[k] = nxt[k];
    }
    float* pb = ws + OFF_PART + ((size_t)(p * Bq + b) * NR) * Nq + j;
#pragma unroll
    for (int h = 0; h < HEADS; h++) pb[(size_t)h * Nq] = lsum[h];
#pragma unroll
    for (int h = 0; h < HEADS; h++)
#pragma unroll
        for (int cc = 0; cc < Cq; cc++)
            pb[(size_t)(HEADS + h * Cq + cc) * Nq] = acc[h][cc];
}

// ---- k2 fused: reduce P partials + hg + ti/tjb (both stored [b][h][n]). ----
// grid (8 j-tiles of 64, Bq), block 256.
template <int P>
__global__ __launch_bounds__(256) void k2_fused(const float* __restrict__ bias_g,
                                                const float* __restrict__ W1,
                                                const float* __restrict__ b1,
                                                float* __restrict__ ws) {
    int b = blockIdx.y;
    int j0 = blockIdx.x * 64;
    int t = threadIdx.x;
    int jl = t & 63;
    int tg = t >> 6;  // 0..3
    __shared__ float red_s[NR * 64];  // 9 KB
    // phase A: sum partials (coalesced: 64 consecutive j per row)
#pragma unroll
    for (int k = 0; k < 9; k++) {
        int r = tg + k * 4;  // covers 0..35
        const float* src = ws + OFF_PART + ((size_t)b * NR + r) * Nq + j0 + jl;
        float s = 0.f;
#pragma unroll
        for (int p = 0; p < P; p++) s += src[(size_t)p * (Bq * NR * Nq)];
        red_s[r * 64 + jl] = s;
    }
    __syncthreads();
    // phase B: hg in regs, 8 heads' worth of W1 dots per thread
    int n = j0 + jl;
    float inv[HEADS];
#pragma unroll
    for (int h = 0; h < HEADS; h++) inv[h] = __builtin_amdgcn_rcpf(red_s[h * 64 + jl]);
    float hg[HID];
#pragma unroll
    for (int r = 0; r < HID; r++)
        hg[r] = red_s[(HEADS + r) * 64 + jl] * inv[r >> 3] + bias_g[r];
#pragma unroll
    for (int hh = 0; hh < 8; hh++) {
        int h = tg * 8 + hh;
        float si = 0.f, sj = 0.f;
#pragma unroll
        for (int d = 0; d < HID; d++) {
            si = fmaf(hg[d], W1[h * 2 * HID + d], si);
            sj = fmaf(hg[d], W1[h * 2 * HID + HID + d], sj);
        }
        ws[OFF_TIT + ((size_t)b * HID + h) * Nq + n] = si;       // coalesced
        ws[OFF_TJB + ((size_t)b * HID + h) * Nq + n] = sj + b1[h];
    }
}

// ---- k3: pairwise score, 2-j register blocking. grid (32, Bq), block 256. ----
// Thread owns jA = tid and jB = tid + 256; every tis[h][ii] broadcast read and
// every packed-mask load is reused for both j's (per-output LDS issue halved).
__global__ __launch_bounds__(256) void k3_score(const float* __restrict__ w2_p,
                                                const float* __restrict__ b2_p,
                                                const float* __restrict__ ws,
                                                float* __restrict__ out) {
    int b = blockIdx.y;
    int i0 = blockIdx.x * 16;
    int j = threadIdx.x;        // jA = j, jB = j + 256
    __shared__ float tis[HID * 16];  // [h][ii]
    for (int t = threadIdx.x; t < HID * 16; t += 256) {
        int h = t >> 4, ii = t & 15;
        tis[t] = ws[OFF_TIT + ((size_t)b * HID + h) * Nq + i0 + ii];
    }
    float tjbA[HID], tjbB[HID];
#pragma unroll
    for (int h = 0; h < HID; h++) {
        const float* row = ws + OFF_TJB + ((size_t)b * HID + h) * Nq;
        tjbA[h] = row[j];
        tjbB[h] = row[j + 256];
    }
    float w2l[HID];
#pragma unroll
    for (int h = 0; h < HID; h++) w2l[h] = w2_p[h];
    float b2 = b2_p[0];
    __syncthreads();
    const uint64_t* packed = (const uint64_t*)(ws + OFF_PACK);
    for (int ii = 0; ii < 16; ii++) {
        int i = i0 + ii;
        const uint64_t* prow = packed + ((size_t)b * Nq + i) * (Nq / 64);
        uint64_t mA = prow[j >> 6];
        uint64_t mB = prow[(j >> 6) + 4];
        int bit = j & 63;       // (j+256)&63 == j&63
        bool onA = (((mA >> bit) & 1ull) != 0) && (i != j);
        bool onB = (((mB >> bit) & 1ull) != 0) && (i != j + 256);
        float sA = b2, sB = b2;
#pragma unroll
        for (int h = 0; h < HID; h++) {
            float ti = tis[h * 16 + ii];  // broadcast LDS read, shared by jA/jB
            float tA = ti + tjbA[h];
            tA = tA > 0.f ? tA : 0.f;
            sA = fmaf(tA, w2l[h], sA);
            float tB = ti + tjbB[h];
            tB = tB > 0.f ? tB : 0.f;
            sB = fmaf(tB, w2l[h], sB);
        }
        float scA = __builtin_amdgcn_rcpf(1.f + __expf(-sA));
        float scB = __builtin_amdgcn_rcpf(1.f + __expf(-sB));
        out[((size_t)b * Nq + i) * Nq + j] = onA ? scA : 0.f;
        out[((size_t)b * Nq + i) * Nq + j + 256] = onB ? scB : 0.f;
    }
}

extern "C" void kernel_launch(void* const* d_in, const int* in_sizes, int n_in,
                              void* d_out, int out_size, void* d_ws, size_t ws_size,
                              hipStream_t stream) {
    const float* x       = (const float*)d_in[0];
    const int*   adj     = (const int*)d_in[1];
    const float* Wp      = (const float*)d_in[2];
    const float* bp      = (const float*)d_in[3];
    const float* Wg      = (const float*)d_in[4];
    const float* att_src = (const float*)d_in[5];
    const float* att_dst = (const float*)d_in[6];
    const float* bias_g  = (const float*)d_in[7];
    const float* W1      = (const float*)d_in[8];
    const float* b1      = (const float*)d_in[9];
    const float* w2      = (const float*)d_in[10];
    const float* b2      = (const float*)d_in[11];
    float* out = (float*)d_out;
    float* ws = (float*)d_ws;

    auto need = [](int P) {
        return (size_t)(OFF_PART + (size_t)P * Bq * NR * Nq) * sizeof(float);
    };

    k0_node<<<dim3(1024), dim3(256), 0, stream>>>(x, Wp, bp, Wg, att_src, att_dst, ws);

    if (ws_size >= need(32)) {
        // P=32 / ICH=16: 1024 blocks -> 4 blocks/CU -> 4 waves/SIMD (was 2).
        k1_aggregate<16><<<dim3(32, 2, Bq), dim3(256), 0, stream>>>(adj, ws);
        k2_fused<32><<<dim3(8, Bq), dim3(256), 0, stream>>>(bias_g, W1, b1, ws);
    } else if (ws_size >= need(16)) {
        k1_aggregate<32><<<dim3(16, 2, Bq), dim3(256), 0, stream>>>(adj, ws);
        k2_fused<16><<<dim3(8, Bq), dim3(256), 0, stream>>>(bias_g, W1, b1, ws);
    } else if (ws_size >= need(8)) {
        k1_aggregate<64><<<dim3(8, 2, Bq), dim3(256), 0, stream>>>(adj, ws);
        k2_fused<8><<<dim3(8, Bq), dim3(256), 0, stream>>>(bias_g, W1, b1, ws);
    } else if (ws_size >= need(4)) {
        k1_aggregate<128><<<dim3(4, 2, Bq), dim3(256), 0, stream>>>(adj, ws);
        k2_fused<4><<<dim3(8, Bq), dim3(256), 0, stream>>>(bias_g, W1, b1, ws);
    } else {
        k1_aggregate<256><<<dim3(2, 2, Bq), dim3(256), 0, stream>>>(adj, ws);
        k2_fused<2><<<dim3(8, Bq), dim3(256), 0, stream>>>(bias_g, W1, b1, ws);
    }

    k3_score<<<dim3(32, Bq), dim3(256), 0, stream>>>(w2, b2, ws, out);
}

// Round 2
// 133.295 us; speedup vs baseline: 1.5578x; 1.5578x over previous
//
#include <hip/hip_runtime.h>
#include <cstdint>

#define Bq 16
#define Nq 512
#define Dq 12
#define HID 32
#define HEADS 4
#define Cq 8

// ws layout (float offsets)
#define OFF_G     0u         // [b][n][32]       262144
#define OFF_AS    262144u    // [b][n][4]         32768
#define OFF_AD    294912u    // [b][n][4]         32768
#define OFF_TIT   327680u    // [b][h][n]        262144  (ti TRANSPOSED)
#define OFF_TJB   589824u    // [b][h][n]        262144
#define OFF_PACK  851968u    // u32 maskT [b][j][16]  (512 KB; bit m of word ig = adj[16m+ig][j])

// ---- k0: per-node h, g, a_s, a_d. 8 nodes/block. ----
__global__ __launch_bounds__(256) void k0_node(
    const float* __restrict__ x, const float* __restrict__ Wp, const float* __restrict__ bp,
    const float* __restrict__ Wg, const float* __restrict__ att_src,
    const float* __restrict__ att_dst, float* __restrict__ ws) {
    __shared__ float xs[8 * Dq];
    __shared__ float hs[8][HID];
    int n_sub = threadIdx.x >> 5;
    int k = threadIdx.x & 31;
    int node0 = blockIdx.x * 8;
    if (threadIdx.x < 8 * Dq) xs[threadIdx.x] = x[(size_t)node0 * Dq + threadIdx.x];
    __syncthreads();
    float s = bp[k];
#pragma unroll
    for (int d = 0; d < Dq; d++) s = fmaf(Wp[k * Dq + d], xs[n_sub * Dq + d], s);
    hs[n_sub][k] = s > 0.f ? s : 0.f;
    __syncthreads();
    float g = 0.f;
#pragma unroll
    for (int d = 0; d < HID; d++) g = fmaf(Wg[k * HID + d], hs[n_sub][d], g);
    int nid = node0 + n_sub;
    ws[OFF_G + (size_t)nid * HID + k] = g;
    float ss = g * att_src[k];   // k = h*8+c
    float sd = g * att_dst[k];
#pragma unroll
    for (int off = 1; off < 8; off <<= 1) {
        ss += __shfl_xor(ss, off);
        sd += __shfl_xor(sd, off);
    }
    if ((k & 7) == 0) {
        int h = k >> 3;
        ws[OFF_AS + (size_t)nid * HEADS + h] = ss;
        ws[OFF_AD + (size_t)nid * HEADS + h] = sd;
    }
}

// ---- k1_fused: softmax-aggregate over ALL i + W1 epilogue, no global partials. ----
// grid (Nq/16=32, Bq), block 256. Thread: jl = t&15 (owns j=j0+jl), ig = t>>4 (i ≡ ig mod 16).
// Per-thread: 32 i's, acc[4][8]+lsum[4] in regs; shfl+LDS reduce over 16 i-groups;
// then hg = acc/lsum + bias_g and the two W1 GEMVs (ti, tjb) fused in-block.
__global__ __launch_bounds__(256, 2) void k1_fused(
    const int* __restrict__ adj, const float* __restrict__ bias_g,
    const float* __restrict__ W1, const float* __restrict__ b1,
    float* __restrict__ ws) {
    int b = blockIdx.y;
    int j0 = blockIdx.x * 16;
    int t = threadIdx.x;
    int jl = t & 15;
    int ig = t >> 4;          // 0..15
    int j = j0 + jl;

    __shared__ float gs[64 * 36];        // chunk of G, rows padded to 36 (16B-aligned, 4-bank spread)
    __shared__ float ass[64 * 4];        // chunk of a_src
    __shared__ float red[36 * 16 * 5];   // [r][jl][w0..w3, total]
    __shared__ float hgs[16 * 36];       // [jl][d]
    __shared__ float W1s[32 * 68];       // W1 rows padded to 68 (4-bank spread, 16B-aligned)

    // stage W1 once (row pad 64 -> 68)
    {
        const float4* src = (const float4*)W1;  // 512 float4
        for (int k = t; k < 512; k += 256) {
            int h = k >> 4, q = k & 15;
            *(float4*)&W1s[h * 68 + q * 4] = src[k];
        }
    }
    float4 adv = *(const float4*)(ws + OFF_AD + ((size_t)b * Nq + j) * HEADS);

    float lsum[HEADS] = {0.f, 0.f, 0.f, 0.f};
    float acc[HEADS][Cq] = {};
    uint32_t mask = 0;

    const int* adjp = adj + ((size_t)b * Nq + ig) * Nq + j;
    const float* Gb = ws + OFF_G + (size_t)b * Nq * HID;
    const float* Ab = ws + OFF_AS + (size_t)b * Nq * HEADS;

    int cur[4], nxt[4];
#pragma unroll
    for (int kk = 0; kk < 4; kk++) cur[kk] = adjp[(size_t)(16 * kk) * Nq];

    for (int c = 0; c < 8; c++) {
        __syncthreads();  // previous chunk's compute done before overwriting LDS
        {   // stage gs: thread covers row ii=t>>2, 8 floats at q*8
            int ii = t >> 2, q = t & 3;
            const float4* s4 = (const float4*)(Gb + (size_t)(c * 64 + ii) * HID + q * 8);
            float4 v0 = s4[0], v1 = s4[1];
            *(float4*)&gs[ii * 36 + q * 8] = v0;
            *(float4*)&gs[ii * 36 + q * 8 + 4] = v1;
            if (t < 64)
                *(float4*)&ass[t * 4] = *(const float4*)(Ab + (size_t)(c * 64 + t) * HEADS);
        }
        if (c < 7) {
#pragma unroll
            for (int kk = 0; kk < 4; kk++)
                nxt[kk] = adjp[(size_t)(64 * (c + 1) + 16 * kk) * Nq];
        }
        __syncthreads();
#pragma unroll
        for (int kk = 0; kk < 4; kk++) {
            int m = 4 * c + kk;          // i = 16m + ig
            int i = 16 * m + ig;
            int a = cur[kk];
            bool msk = (a != 0) || (i == j);
            mask |= (uint32_t)(a != 0) << m;
            int ii = 16 * kk + ig;
            float4 asv = *(const float4*)&ass[ii * 4];
            const float* gr = &gs[ii * 36];
            float zs[HEADS] = {asv.x + adv.x, asv.y + adv.y, asv.z + adv.z, asv.w + adv.w};
#pragma unroll
            for (int h = 0; h < HEADS; h++) {
                float z = zs[h];
                float lk = z > 0.f ? z : 0.2f * z;
                float e = msk ? __expf(lk) : 0.f;   // no max-shift: |z| small
                lsum[h] += e;
                float4 g0 = *(const float4*)(gr + h * 8);
                float4 g1 = *(const float4*)(gr + h * 8 + 4);
                acc[h][0] = fmaf(e, g0.x, acc[h][0]);
                acc[h][1] = fmaf(e, g0.y, acc[h][1]);
                acc[h][2] = fmaf(e, g0.z, acc[h][2]);
                acc[h][3] = fmaf(e, g0.w, acc[h][3]);
                acc[h][4] = fmaf(e, g1.x, acc[h][4]);
                acc[h][5] = fmaf(e, g1.y, acc[h][5]);
                acc[h][6] = fmaf(e, g1.z, acc[h][6]);
                acc[h][7] = fmaf(e, g1.w, acc[h][7]);
            }
        }
#pragma unroll
        for (int kk = 0; kk < 4; kk++) cur[kk] = nxt[kk];
    }

    // transposed adjacency mask for k3: word ig, bit m
    ((uint32_t*)(ws + OFF_PACK))[((size_t)b * Nq + j) * 16 + ig] = mask;

    // reduce over ig: in-wave over ig%4 (lanes differ in bits 4,5), then LDS over 4 waves
    int w = t >> 6;
    auto dump = [&](int r, float v) {
        v += __shfl_xor(v, 16);
        v += __shfl_xor(v, 32);
        if ((t & 63) < 16) red[(r * 16 + jl) * 5 + w] = v;
    };
#pragma unroll
    for (int h = 0; h < HEADS; h++) dump(h, lsum[h]);
#pragma unroll
    for (int h = 0; h < HEADS; h++)
#pragma unroll
        for (int cc = 0; cc < Cq; cc++) dump(4 + h * 8 + cc, acc[h][cc]);
    __syncthreads();
    for (int o = t; o < 576; o += 256) {  // 36 r × 16 j sums over 4 waves
        float* p = &red[o * 5];
        p[4] = (p[0] + p[1]) + (p[2] + p[3]);
    }
    __syncthreads();
    for (int o = t; o < 512; o += 256) {  // hg = acc/lsum + bias_g
        int d = o >> 4, jj = o & 15;
        float s = red[((4 + d) * 16 + jj) * 5 + 4];
        float l = red[((d >> 3) * 16 + jj) * 5 + 4];
        hgs[jj * 36 + d] = s * __builtin_amdgcn_rcpf(l) + bias_g[d];
    }
    __syncthreads();
    // fused k2 epilogue: thread (jl, tg=t>>4) computes h = tg and tg+16
    {
        int tg = t >> 4;
        float si0 = 0.f, sj0 = 0.f, si1 = 0.f, sj1 = 0.f;
        const float* w0 = &W1s[tg * 68];
        const float* w1 = &W1s[(tg + 16) * 68];
        const float* hr = &hgs[jl * 36];
#pragma unroll
        for (int d = 0; d < HID; d++) {
            float hv = hr[d];
            si0 = fmaf(hv, w0[d], si0);
            sj0 = fmaf(hv, w0[32 + d], sj0);
            si1 = fmaf(hv, w1[d], si1);
            sj1 = fmaf(hv, w1[32 + d], sj1);
        }
        ws[OFF_TIT + ((size_t)b * HID + tg) * Nq + j] = si0;
        ws[OFF_TJB + ((size_t)b * HID + tg) * Nq + j] = sj0 + b1[tg];
        ws[OFF_TIT + ((size_t)b * HID + tg + 16) * Nq + j] = si1;
        ws[OFF_TJB + ((size_t)b * HID + tg + 16) * Nq + j] = sj1 + b1[tg + 16];
    }
}

// ---- k3: pairwise score, 2-j register blocking. grid (32, Bq), block 256. ----
// Thread owns jA = tid and jB = tid + 256; tis broadcast reads and the mask words
// are loaded once per thread (64 B contiguous) thanks to the transposed mask layout.
__global__ __launch_bounds__(256) void k3_score(const float* __restrict__ w2_p,
                                                const float* __restrict__ b2_p,
                                                const float* __restrict__ ws,
                                                float* __restrict__ out) {
    int b = blockIdx.y;
    int i0 = blockIdx.x * 16;
    int j = threadIdx.x;        // jA = j, jB = j + 256
    __shared__ float tis[HID * 16];  // [h][ii]
    for (int t = threadIdx.x; t < HID * 16; t += 256) {
        int h = t >> 4, ii = t & 15;
        tis[t] = ws[OFF_TIT + ((size_t)b * HID + h) * Nq + i0 + ii];
    }
    float tjbA[HID], tjbB[HID];
#pragma unroll
    for (int h = 0; h < HID; h++) {
        const float* row = ws + OFF_TJB + ((size_t)b * HID + h) * Nq;
        tjbA[h] = row[j];
        tjbB[h] = row[j + 256];
    }
    float w2l[HID];
#pragma unroll
    for (int h = 0; h < HID; h++) w2l[h] = w2_p[h];
    float b2 = b2_p[0];
    const uint32_t* mrow = (const uint32_t*)(ws + OFF_PACK) + ((size_t)b * Nq + j) * 16;
    uint32_t mtA[16], mtB[16];
#pragma unroll
    for (int wq = 0; wq < 16; wq++) {
        mtA[wq] = mrow[wq];
        mtB[wq] = mrow[256 * 16 + wq];
    }
    int bit = i0 >> 4;  // constant across the ii loop: i>>4 == i0>>4, i&15 == ii
    __syncthreads();
    for (int ii = 0; ii < 16; ii++) {
        int i = i0 + ii;
        bool onA = (((mtA[ii] >> bit) & 1u) != 0) && (i != j);
        bool onB = (((mtB[ii] >> bit) & 1u) != 0) && (i != j + 256);
        float sA = b2, sB = b2;
#pragma unroll
        for (int h = 0; h < HID; h++) {
            float ti = tis[h * 16 + ii];  // broadcast LDS read, shared by jA/jB
            float tA = ti + tjbA[h];
            tA = tA > 0.f ? tA : 0.f;
            sA = fmaf(tA, w2l[h], sA);
            float tB = ti + tjbB[h];
            tB = tB > 0.f ? tB : 0.f;
            sB = fmaf(tB, w2l[h], sB);
        }
        float scA = __builtin_amdgcn_rcpf(1.f + __expf(-sA));
        float scB = __builtin_amdgcn_rcpf(1.f + __expf(-sB));
        out[((size_t)b * Nq + i) * Nq + j] = onA ? scA : 0.f;
        out[((size_t)b * Nq + i) * Nq + j + 256] = onB ? scB : 0.f;
    }
}

extern "C" void kernel_launch(void* const* d_in, const int* in_sizes, int n_in,
                              void* d_out, int out_size, void* d_ws, size_t ws_size,
                              hipStream_t stream) {
    const float* x       = (const float*)d_in[0];
    const int*   adj     = (const int*)d_in[1];
    const float* Wp      = (const float*)d_in[2];
    const float* bp      = (const float*)d_in[3];
    const float* Wg      = (const float*)d_in[4];
    const float* att_src = (const float*)d_in[5];
    const float* att_dst = (const float*)d_in[6];
    const float* bias_g  = (const float*)d_in[7];
    const float* W1      = (const float*)d_in[8];
    const float* b1      = (const float*)d_in[9];
    const float* w2      = (const float*)d_in[10];
    const float* b2      = (const float*)d_in[11];
    float* out = (float*)d_out;
    float* ws = (float*)d_ws;
    (void)in_sizes; (void)n_in; (void)out_size; (void)ws_size;

    k0_node<<<dim3(1024), dim3(256), 0, stream>>>(x, Wp, bp, Wg, att_src, att_dst, ws);
    k1_fused<<<dim3(Nq / 16, Bq), dim3(256), 0, stream>>>(adj, bias_g, W1, b1, ws);
    k3_score<<<dim3(32, Bq), dim3(256), 0, stream>>>(w2, b2, ws, out);
}

// Round 4
// 128.487 us; speedup vs baseline: 1.6161x; 1.0374x over previous
//
#include <hip/hip_runtime.h>
#include <cstdint>

#define Bq 16
#define Nq 512
#define Dq 12
#define HID 32
#define HEADS 4
#define Cq 8

// ws layout (float offsets)
#define OFF_G     0u         // [b][n][32]       262144
#define OFF_AS    262144u    // [b][n][4]         32768
#define OFF_AD    294912u    // [b][n][4]         32768
#define OFF_TIT   327680u    // [b][h][n]        262144  (ti, h-major)
#define OFF_TJBT  589824u    // [b][n][h]        262144  (tj+b1, n-major: contiguous per j)
#define OFF_PACK  851968u    // u32 maskT [b][j][16]  (bit m of word ig = adj[16m+ig][j])

// ---- k0: per-node h, g, a_s, a_d. 8 nodes/block. ----
__global__ __launch_bounds__(256) void k0_node(
    const float* __restrict__ x, const float* __restrict__ Wp, const float* __restrict__ bp,
    const float* __restrict__ Wg, const float* __restrict__ att_src,
    const float* __restrict__ att_dst, float* __restrict__ ws) {
    __shared__ float xs[8 * Dq];
    __shared__ float hs[8][HID];
    int n_sub = threadIdx.x >> 5;
    int k = threadIdx.x & 31;
    int node0 = blockIdx.x * 8;
    if (threadIdx.x < 8 * Dq) xs[threadIdx.x] = x[(size_t)node0 * Dq + threadIdx.x];
    __syncthreads();
    float s = bp[k];
#pragma unroll
    for (int d = 0; d < Dq; d++) s = fmaf(Wp[k * Dq + d], xs[n_sub * Dq + d], s);
    hs[n_sub][k] = s > 0.f ? s : 0.f;
    __syncthreads();
    float g = 0.f;
#pragma unroll
    for (int d = 0; d < HID; d++) g = fmaf(Wg[k * HID + d], hs[n_sub][d], g);
    int nid = node0 + n_sub;
    ws[OFF_G + (size_t)nid * HID + k] = g;
    float ss = g * att_src[k];   // k = h*8+c
    float sd = g * att_dst[k];
#pragma unroll
    for (int off = 1; off < 8; off <<= 1) {
        ss += __shfl_xor(ss, off);
        sd += __shfl_xor(sd, off);
    }
    if ((k & 7) == 0) {
        int h = k >> 3;
        ws[OFF_AS + (size_t)nid * HEADS + h] = ss;
        ws[OFF_AD + (size_t)nid * HEADS + h] = sd;
    }
}

// ---- k1_fused: softmax-aggregate over ALL i + W1 epilogue. ----
// grid (Nq/16=32, Bq), block 256. jl = t&15 (owns j), ig = t>>4 (i ≡ ig mod 16).
// Double-buffered G/a_s chunks, T14 async split (load early / ds_write late),
// ONE barrier per chunk. LDS union: main dbuf vs epilogue red/hgs/W1s/tjs.
// NOTE: no LDS pointer arrays (addrspacecast static-init is rejected); buffers
// selected per-iteration via ternary on (c&1).
__global__ __launch_bounds__(256, 2) void k1_fused(
    const int* __restrict__ adj, const float* __restrict__ bias_g,
    const float* __restrict__ W1, const float* __restrict__ b1,
    float* __restrict__ ws) {
    int b = blockIdx.y;
    int j0 = blockIdx.x * 16;
    int t = threadIdx.x;
    int jl = t & 15;
    int ig = t >> 4;          // 0..15
    int j = j0 + jl;

    __shared__ float smem[6176];
    // main-loop regions: gs buf0 @0 (2304), gs buf1 @2304 (2304),
    //                    as buf0 @4608 (256), as buf1 @4864 (256)
    // epilogue (after final barrier, union with the above):
    float* red = smem;            // 36×16×5 = 2880
    float* hgs = smem + 2880;     // 16×36   = 576
    float* W1s = smem + 3456;     // 32×68   = 2176
    float* tjs = smem + 5632;     // 32×17   = 544

    float4 adv = *(const float4*)(ws + OFF_AD + ((size_t)b * Nq + j) * HEADS);

    const float* Gb = ws + OFF_G + (size_t)b * Nq * HID;
    const float* Ab = ws + OFF_AS + (size_t)b * Nq * HEADS;
    int ii_s = t >> 2, q_s = t & 3;   // staging coords: row ii_s, 8 floats at q_s*8

    // chunk 0: load regs + write LDS (before first barrier)
    float4 ga, gb2;
    float av;
    {
        const float* src = Gb + (size_t)ii_s * HID + q_s * 8;
        ga = *(const float4*)src;
        gb2 = *(const float4*)(src + 4);
        av = Ab[t];
        *(float4*)&smem[ii_s * 36 + q_s * 8] = ga;
        *(float4*)&smem[ii_s * 36 + q_s * 8 + 4] = gb2;
        smem[4608 + t] = av;
    }
    const int* adjp = adj + ((size_t)b * Nq + ig) * Nq + j;
    int cur[4], nxt[4];
#pragma unroll
    for (int kk = 0; kk < 4; kk++) cur[kk] = adjp[(size_t)(16 * kk) * Nq];

    float lsum[HEADS] = {0.f, 0.f, 0.f, 0.f};
    float acc[HEADS][Cq] = {};
    uint32_t mask = 0;

    for (int c = 0; c < 8; c++) {
        __syncthreads();                    // buf c&1 ready; buf (c+1)&1 free
        const float* gsc = (c & 1) ? smem + 2304 : smem;
        const float* asc = (c & 1) ? smem + 4864 : smem + 4608;
        if (c < 7) {                        // T14: issue next-chunk loads EARLY
            const float* src = Gb + (size_t)((c + 1) * 64 + ii_s) * HID + q_s * 8;
            ga = *(const float4*)src;
            gb2 = *(const float4*)(src + 4);
            av = Ab[(c + 1) * 256 + t];
#pragma unroll
            for (int kk = 0; kk < 4; kk++)
                nxt[kk] = adjp[(size_t)(64 * (c + 1) + 16 * kk) * Nq];
        }
#pragma unroll
        for (int kk = 0; kk < 4; kk++) {
            int m = 4 * c + kk;              // i = 16m + ig
            int i = 16 * m + ig;
            int a = cur[kk];
            bool msk = (a != 0) || (i == j);
            mask |= (uint32_t)(a != 0) << m;
            int ii = 16 * kk + ig;
            float4 asv = *(const float4*)&asc[ii * 4];
            const float* gr = &gsc[ii * 36];
            float zs[HEADS] = {asv.x + adv.x, asv.y + adv.y, asv.z + adv.z, asv.w + adv.w};
#pragma unroll
            for (int h = 0; h < HEADS; h++) {
                float z = zs[h];
                float lk = z > 0.f ? z : 0.2f * z;
                float e = msk ? __expf(lk) : 0.f;   // no max-shift: |z| small
                lsum[h] += e;
                float4 g0 = *(const float4*)(gr + h * 8);
                float4 g1 = *(const float4*)(gr + h * 8 + 4);
                acc[h][0] = fmaf(e, g0.x, acc[h][0]);
                acc[h][1] = fmaf(e, g0.y, acc[h][1]);
                acc[h][2] = fmaf(e, g0.z, acc[h][2]);
                acc[h][3] = fmaf(e, g0.w, acc[h][3]);
                acc[h][4] = fmaf(e, g1.x, acc[h][4]);
                acc[h][5] = fmaf(e, g1.y, acc[h][5]);
                acc[h][6] = fmaf(e, g1.z, acc[h][6]);
                acc[h][7] = fmaf(e, g1.w, acc[h][7]);
            }
        }
        if (c < 7) {                        // T14: ds_write LATE (after compute)
            float* gsn = (c & 1) ? smem : smem + 2304;          // buf (c+1)&1
            float* asn = (c & 1) ? smem + 4608 : smem + 4864;
            *(float4*)&gsn[ii_s * 36 + q_s * 8] = ga;
            *(float4*)&gsn[ii_s * 36 + q_s * 8 + 4] = gb2;
            asn[t] = av;
#pragma unroll
            for (int kk = 0; kk < 4; kk++) cur[kk] = nxt[kk];
        }
    }

    // transposed adjacency mask for k3: word ig, bit m
    ((uint32_t*)(ws + OFF_PACK))[((size_t)b * Nq + j) * 16 + ig] = mask;

    __syncthreads();   // all reads of gs/ass done -> union region reusable

    // stage W1 (row pad 64 -> 68) into the union region
    {
        const float4* src = (const float4*)W1;  // 512 float4
        for (int k = t; k < 512; k += 256) {
            int h = k >> 4, q = k & 15;
            *(float4*)&W1s[h * 68 + q * 4] = src[k];
        }
    }
    // reduce over ig: in-wave over 4 igs (bits 4,5 of t), then LDS over 4 waves
    int w = t >> 6;
    auto dump = [&](int r, float v) {
        v += __shfl_xor(v, 16);
        v += __shfl_xor(v, 32);
        if ((t & 63) < 16) red[(r * 16 + jl) * 5 + w] = v;
    };
#pragma unroll
    for (int h = 0; h < HEADS; h++) dump(h, lsum[h]);
#pragma unroll
    for (int h = 0; h < HEADS; h++)
#pragma unroll
        for (int cc = 0; cc < Cq; cc++) dump(4 + h * 8 + cc, acc[h][cc]);
    __syncthreads();
    for (int o = t; o < 576; o += 256) {  // 36 r × 16 j totals over 4 waves
        float* p = &red[o * 5];
        p[4] = (p[0] + p[1]) + (p[2] + p[3]);
    }
    __syncthreads();
    for (int o = t; o < 512; o += 256) {  // hg = acc/lsum + bias_g
        int d = o >> 4, jj = o & 15;
        float s = red[((4 + d) * 16 + jj) * 5 + 4];
        float l = red[((d >> 3) * 16 + jj) * 5 + 4];
        hgs[jj * 36 + d] = s * __builtin_amdgcn_rcpf(l) + bias_g[d];
    }
    __syncthreads();
    // fused W1 epilogue: thread (jl, tg) computes h = tg and tg+16
    {
        int tg = t >> 4;
        float si0 = 0.f, sj0 = 0.f, si1 = 0.f, sj1 = 0.f;
        const float* w0 = &W1s[tg * 68];
        const float* w1 = &W1s[(tg + 16) * 68];
        const float* hr = &hgs[jl * 36];
#pragma unroll
        for (int d = 0; d < HID; d++) {
            float hv = hr[d];
            si0 = fmaf(hv, w0[d], si0);
            sj0 = fmaf(hv, w0[32 + d], sj0);
            si1 = fmaf(hv, w1[d], si1);
            sj1 = fmaf(hv, w1[32 + d], sj1);
        }
        ws[OFF_TIT + ((size_t)b * HID + tg) * Nq + j] = si0;        // coalesced (h-major)
        ws[OFF_TIT + ((size_t)b * HID + tg + 16) * Nq + j] = si1;
        tjs[tg * 17 + jl] = sj0 + b1[tg];            // pad 17: conflict-free transpose
        tjs[(tg + 16) * 17 + jl] = sj1 + b1[tg + 16];
    }
    __syncthreads();
    // coalesced transposed store of tj+b1: [b][n][h]
    for (int o = t; o < 512; o += 256) {
        int jj = o >> 5, h = o & 31;
        ws[OFF_TJBT + ((size_t)b * Nq + j0 + jj) * HID + h] = tjs[h * 17 + jj];
    }
}

// ---- k3: pairwise score, 2-j blocking, float4-broadcast tis, fully unrolled. ----
// grid (32, Bq), block 256. Thread owns jA = tid, jB = tid + 256.
__global__ __launch_bounds__(256) void k3_score(const float* __restrict__ w2_p,
                                                const float* __restrict__ b2_p,
                                                const float* __restrict__ ws,
                                                float* __restrict__ out) {
    int b = blockIdx.y;
    int i0 = blockIdx.x * 16;
    int j = threadIdx.x;        // jA = j, jB = j + 256
    __shared__ float tisT[16 * 36];  // [ii][h], row pad 36 (16B-aligned rows)
    {
        int h = threadIdx.x >> 4, ii = threadIdx.x & 15;
        tisT[ii * 36 + h] = ws[OFF_TIT + ((size_t)b * HID + h) * Nq + i0 + ii];
        tisT[ii * 36 + h + 16] = ws[OFF_TIT + ((size_t)b * HID + h + 16) * Nq + i0 + ii];
    }
    // tj+b1: 32 contiguous floats per j thanks to [n][h] layout
    float4 ta[8], tb[8];
    const float* rA = ws + OFF_TJBT + ((size_t)b * Nq + j) * HID;
    const float* rB = rA + (size_t)256 * HID;
#pragma unroll
    for (int q = 0; q < 8; q++) {
        ta[q] = *(const float4*)(rA + q * 4);
        tb[q] = *(const float4*)(rB + q * 4);
    }
    float w2l[HID];
#pragma unroll
    for (int h = 0; h < HID; h++) w2l[h] = w2_p[h];
    float b2 = b2_p[0];
    const uint32_t* mrow = (const uint32_t*)(ws + OFF_PACK) + ((size_t)b * Nq + j) * 16;
    uint4 mAv[4], mBv[4];
#pragma unroll
    for (int q = 0; q < 4; q++) {
        mAv[q] = ((const uint4*)mrow)[q];
        mBv[q] = ((const uint4*)(mrow + 256 * 16))[q];
    }
    int bit = i0 >> 4;  // word index = ii, bit = i0>>4 (i0 multiple of 16)
    __syncthreads();
#pragma unroll
    for (int ii = 0; ii < 16; ii++) {   // FULL unroll: all array indices static
        int i = i0 + ii;
        uint32_t mA = (ii & 3) == 0 ? mAv[ii >> 2].x : (ii & 3) == 1 ? mAv[ii >> 2].y
                    : (ii & 3) == 2 ? mAv[ii >> 2].z : mAv[ii >> 2].w;
        uint32_t mB = (ii & 3) == 0 ? mBv[ii >> 2].x : (ii & 3) == 1 ? mBv[ii >> 2].y
                    : (ii & 3) == 2 ? mBv[ii >> 2].z : mBv[ii >> 2].w;
        bool onA = (((mA >> bit) & 1u) != 0) && (i != j);
        bool onB = (((mB >> bit) & 1u) != 0) && (i != j + 256);
        float sA = b2, sB = b2;
#pragma unroll
        for (int q = 0; q < 8; q++) {
            float4 tq = *(const float4*)&tisT[ii * 36 + q * 4];  // broadcast b128
#pragma unroll
            for (int e = 0; e < 4; e++) {
                float ti = (e == 0) ? tq.x : (e == 1) ? tq.y : (e == 2) ? tq.z : tq.w;
                float tjA = (e == 0) ? ta[q].x : (e == 1) ? ta[q].y : (e == 2) ? ta[q].z : ta[q].w;
                float tjB = (e == 0) ? tb[q].x : (e == 1) ? tb[q].y : (e == 2) ? tb[q].z : tb[q].w;
                float tA = ti + tjA;
                tA = tA > 0.f ? tA : 0.f;
                sA = fmaf(tA, w2l[q * 4 + e], sA);
                float tB = ti + tjB;
                tB = tB > 0.f ? tB : 0.f;
                sB = fmaf(tB, w2l[q * 4 + e], sB);
            }
        }
        float scA = __builtin_amdgcn_rcpf(1.f + __expf(-sA));
        float scB = __builtin_amdgcn_rcpf(1.f + __expf(-sB));
        out[((size_t)b * Nq + i) * Nq + j] = onA ? scA : 0.f;
        out[((size_t)b * Nq + i) * Nq + j + 256] = onB ? scB : 0.f;
    }
}

extern "C" void kernel_launch(void* const* d_in, const int* in_sizes, int n_in,
                              void* d_out, int out_size, void* d_ws, size_t ws_size,
                              hipStream_t stream) {
    const float* x       = (const float*)d_in[0];
    const int*   adj     = (const int*)d_in[1];
    const float* Wp      = (const float*)d_in[2];
    const float* bp      = (const float*)d_in[3];
    const float* Wg      = (const float*)d_in[4];
    const float* att_src = (const float*)d_in[5];
    const float* att_dst = (const float*)d_in[6];
    const float* bias_g  = (const float*)d_in[7];
    const float* W1      = (const float*)d_in[8];
    const float* b1      = (const float*)d_in[9];
    const float* w2      = (const float*)d_in[10];
    const float* b2      = (const float*)d_in[11];
    float* out = (float*)d_out;
    float* ws = (float*)d_ws;
    (void)in_sizes; (void)n_in; (void)out_size; (void)ws_size;

    k0_node<<<dim3(1024), dim3(256), 0, stream>>>(x, Wp, bp, Wg, att_src, att_dst, ws);
    k1_fused<<<dim3(Nq / 16, Bq), dim3(256), 0, stream>>>(adj, bias_g, W1, b1, ws);
    k3_score<<<dim3(32, Bq), dim3(256), 0, stream>>>(w2, b2, ws, out);
}